// Round 3
// baseline (474.415 us; speedup 1.0000x reference)
//
#include <hip/hip_runtime.h>
#include <cstdint>

// Problem constants
constexpr int B_   = 16;
constexpr int CIN  = 128;
constexpr int H_   = 224;
constexpr int W_   = 224;
constexpr int COUT = 256;
constexpr int HOUT = 112;
constexpr int WOUT = 75;

// Tiling
constexpr int OWP  = 80;            // padded ow per output row
constexpr int BM   = 160;           // 2 output rows x 80
constexpr int BN   = 128;           // out-channels per block
constexpr int CI_SC = 16;           // input channels per super-chunk
constexpr int KSC  = CI_SC * 9;     // 144 k per super-chunk
constexpr int NSC  = CIN / CI_SC;   // 8 super-chunks
constexpr int THREADS = 256;

constexpr int W_ELEMS = COUT * CIN * 9;          // 294912 weights
constexpr size_t WS_NEED = (size_t)W_ELEMS * 2;  // bf16 bytes

typedef float f32x16 __attribute__((ext_vector_type(16)));
typedef short short8 __attribute__((ext_vector_type(8)));

struct U64x2 { unsigned long long lo, hi; };

__device__ inline unsigned cvtpk(float a, float b) {
  unsigned r;
  asm("v_cvt_pk_bf16_f32 %0, %1, %2" : "=v"(r) : "v"(a), "v"(b));
  return r;  // low16 = bf16(a), high16 = bf16(b)
}

// ---- prepass: fp32 weights -> bf16 in ws ----
__global__ __launch_bounds__(256) void wprep(const float* __restrict__ wgt,
                                             unsigned* __restrict__ ws) {
  int id = blockIdx.x * 256 + threadIdx.x;          // one float4 -> one uint2
  const float4 w4 = reinterpret_cast<const float4*>(wgt)[id];
  uint2 o;
  o.x = cvtpk(w4.x, w4.y);
  o.y = cvtpk(w4.z, w4.w);
  reinterpret_cast<uint2*>(ws)[id] = o;
}

template <int WS>
__global__ __launch_bounds__(THREADS, 3) void conv_mfma(
    const float* __restrict__ x, const float* __restrict__ wgt,
    const short8* __restrict__ wbf, const float* __restrict__ bias,
    float* __restrict__ out) {

  // LDS A-tile: [KSC][BM] bf16 in [4k x 16m] subtiles:
  // byte(k,m) = ((k>>2)*10 + (m>>4))*128 + (k&3)*32 + (m&15)*2
  __shared__ __align__(16) unsigned char smem[KSC * BM * 2];

  // XCD-chunked bijective swizzle: 1792 blocks = 8 XCDs * 224
  int Lid   = (blockIdx.x & 7) * 224 + (blockIdx.x >> 3);
  int coBlk = Lid & 1;
  int t     = Lid >> 1;
  int ohp   = t % 56;
  int b     = t / 56;
  int oh_base = ohp * 2;

  const int tid  = threadIdx.x;
  const int lane = tid & 63;
  const int wv   = tid >> 6;

  const float* xb = x + (size_t)b * CIN * H_ * W_;
  const int co_lane = coBlk * BN + wv * 32 + (lane & 31);
  const float* wrow = wgt + (size_t)co_lane * (CIN * 9);
  const short8* wrow8 = wbf + (size_t)co_lane * (CIN * 9 / 8);   // 144 short8/row
  const int half = lane >> 5;

  const unsigned sbase = (unsigned)(uintptr_t)&smem[0];
  const unsigned abase = sbase
      + ((2u * (lane >> 5)) * 10u + ((lane >> 4) & 1u)) * 128u
      + (lane & 15) * 8u;

  f32x16 acc[5];
#pragma unroll
  for (int mf = 0; mf < 5; ++mf)
#pragma unroll
    for (int i = 0; i < 16; ++i) acc[mf][i] = 0.f;

  unsigned long long ta0[10], ta1[10];

  for (int sc = 0; sc < NSC; ++sc) {
    if (sc) __syncthreads();

    // ---- stage super-chunk: vectorized, statically unrolled ----
#pragma unroll
    for (int j = 0; j < 8; ++j) {
      int it = tid + 256 * j;
      if (it < CI_SC * 6 * 19) {
        int ci  = it & 15;
        int r   = it >> 4;
        int g   = r % 19;
        int t3  = r / 19;
        int kh  = t3 % 3;
        int ohl = t3 / 3;

        int ih = 2 * (oh_base + ohl) - 1 + kh;
        bool rowok = (unsigned)ih < (unsigned)H_;
        const float* row = xb + ((size_t)(sc * CI_SC + ci) * H_ + (rowok ? ih : 0)) * W_;
        int iwb = 12 * g;                      // elements needed: iw = iwb-1 .. iwb+10

        float f[12];
        if (rowok) {
          // aligned float4 loads; third clamped (garbage lands only in ow>=75, discarded)
          float4 a4 = *reinterpret_cast<const float4*>(row + iwb);
          float4 b4 = *reinterpret_cast<const float4*>(row + iwb + 4);
          float4 c4 = *reinterpret_cast<const float4*>(row + (iwb + 8 > 220 ? 220 : iwb + 8));
          f[0]  = g ? row[iwb - 1] : 0.f;      // left pad
          f[1]  = a4.x; f[2]  = a4.y; f[3]  = a4.z; f[4]  = a4.w;
          f[5]  = b4.x; f[6]  = b4.y; f[7]  = b4.z; f[8]  = b4.w;
          f[9]  = c4.x; f[10] = c4.y; f[11] = c4.z;
        } else {
#pragma unroll
          for (int e = 0; e < 12; ++e) f[e] = 0.f;
        }

        // element e -> (kw = e%3, ow = 4g + e/3); one b64 write per kw
#pragma unroll
        for (int kw = 0; kw < 3; ++kw) {
          unsigned lo = cvtpk(f[kw],     f[kw + 3]);
          unsigned hi = cvtpk(f[kw + 6], f[kw + 9]);
          int k = ci * 9 + kh * 3 + kw;
          int m = ohl * OWP + 4 * g;
          unsigned byte = (unsigned)(((k >> 2) * 10 + (m >> 4)) * 128 + (k & 3) * 32 + (m & 15) * 2);
          *reinterpret_cast<uint2*>(&smem[byte]) = make_uint2(lo, hi);
        }
      }
    }
    __syncthreads();

    // ---- compute: 9 MFMA k-chunks, 1-deep tr-read pipeline ----
    auto issue = [&](int kc, unsigned long long* tt) {
#pragma unroll
      for (int mf = 0; mf < 5; ++mf) {
        unsigned a1 = abase + (unsigned)(kc * 5120 + mf * 256);
        asm volatile("ds_read_b64_tr_b16 %0, %1" : "=v"(tt[2 * mf]) : "v"(a1));
        asm volatile("ds_read_b64_tr_b16 %0, %1 offset:1280" : "=v"(tt[2 * mf + 1]) : "v"(a1));
      }
    };

    issue(0, ta0);
#pragma unroll
    for (int kc = 0; kc < 9; ++kc) {
      unsigned long long* cur = (kc & 1) ? ta1 : ta0;
      unsigned long long* nxt = (kc & 1) ? ta0 : ta1;
      if (kc < 8) {
        issue(kc + 1, nxt);
        asm volatile("s_waitcnt lgkmcnt(10)" ::: "memory");
      } else {
        asm volatile("s_waitcnt lgkmcnt(0)" ::: "memory");
      }
      __builtin_amdgcn_sched_barrier(0);

      // B fragment
      short8 bfrag;
      if (WS) {
        bfrag = wrow8[sc * 18 + kc * 2 + half];
      } else {
        int kg = sc * KSC + kc * 16 + half * 8;
        const float4* wp4 = reinterpret_cast<const float4*>(wrow + kg);
        float4 f0 = wp4[0], f1 = wp4[1];
        unsigned p0 = cvtpk(f0.x, f0.y), p1 = cvtpk(f0.z, f0.w);
        unsigned p2 = cvtpk(f1.x, f1.y), p3 = cvtpk(f1.z, f1.w);
        uint4 u{p0, p1, p2, p3};
        bfrag = __builtin_bit_cast(short8, u);
      }

#pragma unroll
      for (int mf = 0; mf < 5; ++mf) {
        U64x2 u{cur[2 * mf], cur[2 * mf + 1]};
        short8 afrag = __builtin_bit_cast(short8, u);
        acc[mf] = __builtin_amdgcn_mfma_f32_32x32x16_bf16(afrag, bfrag, acc[mf], 0, 0, 0);
      }
    }
  }

  // ---- epilogue: C layout col=lane&31 (co), row=(r&3)+8*(r>>2)+4*(lane>>5) (m) ----
  float bv = bias[co_lane];
#pragma unroll
  for (int mf = 0; mf < 5; ++mf) {
#pragma unroll
    for (int r = 0; r < 16; ++r) {
      int m   = mf * 32 + (r & 3) + 8 * (r >> 2) + 4 * (lane >> 5);
      int ohl = m >= OWP ? 1 : 0;
      int ow  = m - OWP * ohl;
      if (ow < WOUT) {
        int oh = oh_base + ohl;
        out[(((size_t)b * COUT + co_lane) * HOUT + oh) * WOUT + ow] = acc[mf][r] + bv;
      }
    }
  }
}

extern "C" void kernel_launch(void* const* d_in, const int* in_sizes, int n_in,
                              void* d_out, int out_size, void* d_ws, size_t ws_size,
                              hipStream_t stream) {
  const float* x    = (const float*)d_in[0];
  const float* wgt  = (const float*)d_in[1];
  const float* bias = (const float*)d_in[2];
  float* out        = (float*)d_out;

  dim3 grid(16 * 56 * 2);
  dim3 block(THREADS);

  if (ws_size >= WS_NEED) {
    wprep<<<dim3(W_ELEMS / 4 / 256), dim3(256), 0, stream>>>(wgt, (unsigned*)d_ws);
    conv_mfma<1><<<grid, block, 0, stream>>>(x, wgt, (const short8*)d_ws, bias, out);
  } else {
    conv_mfma<0><<<grid, block, 0, stream>>>(x, wgt, (const short8*)d_ws, bias, out);
  }
}

// Round 5
// 379.649 us; speedup vs baseline: 1.2496x; 1.2496x over previous
//
#include <hip/hip_runtime.h>
#include <cstdint>

constexpr int B_   = 16;
constexpr int CIN  = 128;
constexpr int H_   = 224;
constexpr int W_   = 224;
constexpr int COUT = 256;
constexpr int HOUT = 112;
constexpr int WOUT = 75;

constexpr int OWP   = 80;     // padded ow per output row
constexpr int BM    = 160;    // 2 output rows
constexpr int CI_SC = 16;     // input channels per super-chunk
constexpr int KSC_R = 144;    // real k per super-chunk
constexpr int KP    = 160;    // padded k per super-chunk (5 x K=32)
constexpr int NSC   = 8;
constexpr int THREADS = 512;  // 8 waves: 2 m-halves x 4 co-groups

constexpr int WS_ELEMS = COUT * KP * NSC;          // 327680 bf16
constexpr size_t WS_NEED = (size_t)WS_ELEMS * 2;   // 655360 B

typedef float  f32x4  __attribute__((ext_vector_type(4)));
typedef short  short8 __attribute__((ext_vector_type(8)));

struct U64x2 { unsigned long long lo, hi; };
__device__ inline short8 bc8(unsigned long long a, unsigned long long b) {
  U64x2 u{a, b};
  return __builtin_bit_cast(short8, u);
}

__device__ inline unsigned cvtpk(float a, float b) {
  unsigned r;
  asm("v_cvt_pk_bf16_f32 %0, %1, %2" : "=v"(r) : "v"(a), "v"(b));
  return r;  // lo16 = bf16(a), hi16 = bf16(b)
}

// ---- prepass: fp32 weights -> bf16 in ws, layout [co][sc][160], k>=144 zeroed ----
__global__ __launch_bounds__(256) void wprep(const float* __restrict__ wgt,
                                             uint2* __restrict__ ws) {
  int id = blockIdx.x * 256 + threadIdx.x;   // 81920 threads, 4 bf16 each
  int k4 = id % 40;
  int cs = id / 40;
  int sc = cs & 7;
  int co = cs >> 3;
  float f[4];
#pragma unroll
  for (int e = 0; e < 4; ++e) {
    int k = k4 * 4 + e;
    float v = 0.f;
    if (k < KSC_R) {
      int ci = k / 9, r = k - ci * 9;
      v = wgt[((size_t)co * CIN + sc * CI_SC + ci) * 9 + r];
    }
    f[e] = v;
  }
  ws[id] = make_uint2(cvtpk(f[0], f[1]), cvtpk(f[2], f[3]));
}

template <int WS>
__device__ __forceinline__ void get_b(const short8* w0p, const short8* w1p,
                                      const float* wg0, const float* wg1,
                                      int kc, int g, short8& b0, short8& b1) {
  if (WS) {
    b0 = w0p[kc * 4];
    b1 = w1p[kc * 4];
  } else {
    if (kc == 4 && g >= 2) { b0 = short8{}; b1 = short8{}; }
    else {
      const float* p0 = wg0 + kc * 32;
      const float* p1 = wg1 + kc * 32;
      float4 x0 = *(const float4*)p0, x1 = *(const float4*)(p0 + 4);
      float4 y0 = *(const float4*)p1, y1 = *(const float4*)(p1 + 4);
      uint4 u0{cvtpk(x0.x, x0.y), cvtpk(x0.z, x0.w), cvtpk(x1.x, x1.y), cvtpk(x1.z, x1.w)};
      uint4 u1{cvtpk(y0.x, y0.y), cvtpk(y0.z, y0.w), cvtpk(y1.x, y1.y), cvtpk(y1.z, y1.w)};
      b0 = __builtin_bit_cast(short8, u0);
      b1 = __builtin_bit_cast(short8, u1);
    }
  }
}

// issue the 10 tr reads for one K=32 chunk: SET{2mf} = k 8g..8g+3, SET{2mf+1} = k 8g+4..8g+7
#define TR_ISSUE(S, KC)                                                                   \
  {                                                                                       \
    unsigned a_ = abase + (unsigned)((KC) * 10240);                                       \
    asm volatile("ds_read_b64_tr_b16 %0, %1"             : "=v"(S##0) : "v"(a_));         \
    asm volatile("ds_read_b64_tr_b16 %0, %1 offset:1280" : "=v"(S##1) : "v"(a_));         \
    asm volatile("ds_read_b64_tr_b16 %0, %1 offset:128"  : "=v"(S##2) : "v"(a_));         \
    asm volatile("ds_read_b64_tr_b16 %0, %1 offset:1408" : "=v"(S##3) : "v"(a_));         \
    asm volatile("ds_read_b64_tr_b16 %0, %1 offset:256"  : "=v"(S##4) : "v"(a_));         \
    asm volatile("ds_read_b64_tr_b16 %0, %1 offset:1536" : "=v"(S##5) : "v"(a_));         \
    asm volatile("ds_read_b64_tr_b16 %0, %1 offset:384"  : "=v"(S##6) : "v"(a_));         \
    asm volatile("ds_read_b64_tr_b16 %0, %1 offset:1664" : "=v"(S##7) : "v"(a_));         \
    asm volatile("ds_read_b64_tr_b16 %0, %1 offset:512"  : "=v"(S##8) : "v"(a_));         \
    asm volatile("ds_read_b64_tr_b16 %0, %1 offset:1792" : "=v"(S##9) : "v"(a_));         \
  }

#define MFMA_SET(S)                                                                       \
  {                                                                                       \
    short8 a0_ = bc8(S##0, S##1);                                                         \
    short8 a1_ = bc8(S##2, S##3);                                                         \
    short8 a2_ = bc8(S##4, S##5);                                                         \
    short8 a3_ = bc8(S##6, S##7);                                                         \
    short8 a4_ = bc8(S##8, S##9);                                                         \
    acc[0][0] = __builtin_amdgcn_mfma_f32_16x16x32_bf16(a0_, bf0_, acc[0][0], 0, 0, 0);   \
    acc[0][1] = __builtin_amdgcn_mfma_f32_16x16x32_bf16(a0_, bf1_, acc[0][1], 0, 0, 0);   \
    acc[1][0] = __builtin_amdgcn_mfma_f32_16x16x32_bf16(a1_, bf0_, acc[1][0], 0, 0, 0);   \
    acc[1][1] = __builtin_amdgcn_mfma_f32_16x16x32_bf16(a1_, bf1_, acc[1][1], 0, 0, 0);   \
    acc[2][0] = __builtin_amdgcn_mfma_f32_16x16x32_bf16(a2_, bf0_, acc[2][0], 0, 0, 0);   \
    acc[2][1] = __builtin_amdgcn_mfma_f32_16x16x32_bf16(a2_, bf1_, acc[2][1], 0, 0, 0);   \
    acc[3][0] = __builtin_amdgcn_mfma_f32_16x16x32_bf16(a3_, bf0_, acc[3][0], 0, 0, 0);   \
    acc[3][1] = __builtin_amdgcn_mfma_f32_16x16x32_bf16(a3_, bf1_, acc[3][1], 0, 0, 0);   \
    acc[4][0] = __builtin_amdgcn_mfma_f32_16x16x32_bf16(a4_, bf0_, acc[4][0], 0, 0, 0);   \
    acc[4][1] = __builtin_amdgcn_mfma_f32_16x16x32_bf16(a4_, bf1_, acc[4][1], 0, 0, 0);   \
  }

#define KSTEP(KC)                                                                         \
  {                                                                                       \
    short8 bf0_, bf1_;                                                                    \
    get_b<WS>(w0p, w1p, wg0, wg1, (KC), g, bf0_, bf1_);                                   \
    TR_ISSUE(tA, (KC));                                                                   \
    asm volatile("s_waitcnt lgkmcnt(0)" ::: "memory");                                    \
    __builtin_amdgcn_sched_barrier(0);                                                    \
    __builtin_amdgcn_s_setprio(1);                                                        \
    MFMA_SET(tA);                                                                         \
    __builtin_amdgcn_s_setprio(0);                                                        \
  }

template <int WS>
__global__ __launch_bounds__(THREADS, 4) void conv_mfma(
    const float* __restrict__ x, const float* __restrict__ wgt,
    const short8* __restrict__ wbf, const float* __restrict__ bias,
    float* __restrict__ out) {

  // LDS A-tile: [KP=160 k][BM=160 m] bf16, [4k x 16m] subtiles:
  // byte(k,m) = ((k>>2)*10 + (m>>4))*128 + (k&3)*32 + (m&15)*2   (51200 B)
  __shared__ __align__(16) unsigned char smem[KP * BM * 2];

  // XCD-chunked bijective swizzle: 1792 blocks = 8 XCDs * 224
  int Lid   = (blockIdx.x & 7) * 224 + (blockIdx.x >> 3);
  int coBlk = Lid & 1;
  int t     = Lid >> 1;
  int ohp   = t % 56;
  int b     = t / 56;
  int oh_base = ohp * 2;

  const int tid   = threadIdx.x;
  const int lane  = tid & 63;
  const int wv    = tid >> 6;
  const int mhalf = wv >> 2;          // 0,1 -> output row
  const int cogrp = wv & 3;           // 4 co-groups of 32
  const int g     = lane >> 4;        // k-lane-group
  const int l15   = lane & 15;

  const float* xb = x + (size_t)b * CIN * H_ * W_;
  const int coB_  = coBlk * 128 + cogrp * 32 + l15;

  const unsigned sbase = (unsigned)(uintptr_t)&smem[0];
  const unsigned abase = sbase + (unsigned)(g * 2560 + mhalf * 5 * 128 + l15 * 8);

  // NaN fix: k-rows 144..159 are never staged (weights there are 0, but
  // garbage-A * 0 = NaN if garbage is Inf/NaN). Zero them once; the region is
  // contiguous: k>=144 <=> byte >= 36*10*128 = 46080 (5120 B).
  if (tid < 320) {
    *reinterpret_cast<uint4*>(&smem[46080 + tid * 16]) = uint4{0u, 0u, 0u, 0u};
  }

  // ---- sc-invariant staging precompute (3.56 items/thread) ----
  int      aoff[4], moff[4], coff[4];
  unsigned lb0[4], lb1[4], lb2[4], mA[4], mF[4];
#pragma unroll
  for (int j = 0; j < 4; ++j) {
    int it  = tid + THREADS * j;
    int ci  = it & 15;
    int r   = it >> 4;
    int gg  = r % 19;
    int t3  = r / 19;
    int kh  = t3 % 3;
    int ohl = t3 / 3;
    int ih  = 2 * (oh_base + ohl) - 1 + kh;
    bool rowok = (unsigned)ih < (unsigned)H_;
    int ro  = (ci * H_ + (rowok ? ih : 0)) * W_;
    int iwb = 12 * gg;
    aoff[j] = ro + iwb;
    moff[j] = ro + iwb - (gg ? 1 : 0);
    coff[j] = ro + (iwb + 8 > 220 ? 220 : iwb + 8);
    int k = ci * 9 + kh * 3;
    int m = ohl * OWP + 4 * gg;
    auto byteOf = [](int kk, int mm) -> unsigned {
      return (unsigned)(((kk >> 2) * 10 + (mm >> 4)) * 128 + (kk & 3) * 32 + (mm & 15) * 2);
    };
    lb0[j] = byteOf(k, m); lb1[j] = byteOf(k + 1, m); lb2[j] = byteOf(k + 2, m);
    mA[j] = rowok ? 0xFFFFFFFFu : 0u;
    mF[j] = mA[j] & (gg ? 0xFFFFFFFFu : 0xFFFF0000u);
  }

  f32x4 acc[5][2];
#pragma unroll
  for (int mf = 0; mf < 5; ++mf)
#pragma unroll
    for (int cf = 0; cf < 2; ++cf)
#pragma unroll
      for (int i = 0; i < 4; ++i) acc[mf][cf][i] = 0.f;

  const int w0off = coB_ * 160 + g;                 // short8 units
  unsigned long long tA0, tA1, tA2, tA3, tA4, tA5, tA6, tA7, tA8, tA9;

  for (int sc = 0; sc < NSC; ++sc) {
    if (sc) __syncthreads();

    // ---- stage: 1824 items, vectorized fp32 loads -> cvtpk -> de-interleaved b64 LDS writes ----
    const float* xs = xb + (size_t)sc * (CI_SC * H_ * W_);
#pragma unroll
    for (int j = 0; j < 4; ++j) {
      if (j < 3 || tid < 288) {
        const float* ap = xs + aoff[j];
        float4 a4 = *(const float4*)ap;
        float4 b4 = *(const float4*)(ap + 4);
        float4 c4 = *(const float4*)(xs + coff[j]);
        float fm1 = xs[moff[j]];
        // element e -> (kw = e%3, ow = 4g + e/3); f = [fm1, a4.xyzw, b4.xyzw, c4.xyz]
        unsigned l0 = cvtpk(fm1,  a4.z) & mF[j];
        unsigned h0 = cvtpk(b4.y, c4.x) & mA[j];
        unsigned l1 = cvtpk(a4.x, a4.w) & mA[j];
        unsigned h1 = cvtpk(b4.z, c4.y) & mA[j];
        unsigned l2 = cvtpk(a4.y, b4.x) & mA[j];
        unsigned h2 = cvtpk(b4.w, c4.z) & mA[j];
        *(uint2*)&smem[lb0[j]] = make_uint2(l0, h0);
        *(uint2*)&smem[lb1[j]] = make_uint2(l1, h1);
        *(uint2*)&smem[lb2[j]] = make_uint2(l2, h2);
      }
    }
    __syncthreads();

    // ---- compute: 5 x K=32 ----
    const short8* w0p = wbf + w0off + sc * 20;
    const short8* w1p = w0p + 2560;                 // +16 co
    const float*  wg0 = wgt + (size_t)coB_ * 1152 + sc * 144 + g * 8;
    const float*  wg1 = wg0 + (size_t)16 * 1152;
    KSTEP(0) KSTEP(1) KSTEP(2) KSTEP(3) KSTEP(4)
  }

  // ---- epilogue: C frag col(co)=l15, row(m)=g*4+r ----
  float bv0 = bias[coB_];
  float bv1 = bias[coB_ + 16];
  int oh = oh_base + mhalf;
  size_t ob0 = (((size_t)b * COUT + coB_) * HOUT + oh) * WOUT;
  size_t ob1 = ob0 + (size_t)16 * HOUT * WOUT;
#pragma unroll
  for (int mf = 0; mf < 5; ++mf) {
    int owb = mf * 16 + g * 4;
#pragma unroll
    for (int r = 0; r < 4; ++r) {
      int ow = owb + r;
      if (ow < WOUT) {
        out[ob0 + ow] = acc[mf][0][r] + bv0;
        out[ob1 + ow] = acc[mf][1][r] + bv1;
      }
    }
  }
}

extern "C" void kernel_launch(void* const* d_in, const int* in_sizes, int n_in,
                              void* d_out, int out_size, void* d_ws, size_t ws_size,
                              hipStream_t stream) {
  const float* x    = (const float*)d_in[0];
  const float* wgt  = (const float*)d_in[1];
  const float* bias = (const float*)d_in[2];
  float* out        = (float*)d_out;

  dim3 grid(16 * 56 * 2);
  dim3 block(THREADS);

  if (ws_size >= WS_NEED) {
    wprep<<<dim3(WS_ELEMS / 4 / 256), dim3(256), 0, stream>>>(wgt, (uint2*)d_ws);
    conv_mfma<1><<<grid, block, 0, stream>>>(x, wgt, (const short8*)d_ws, bias, out);
  } else {
    conv_mfma<0><<<grid, block, 0, stream>>>(x, wgt, (const short8*)d_ws, bias, out);
  }
}

// Round 6
// 344.766 us; speedup vs baseline: 1.3760x; 1.1012x over previous
//
#include <hip/hip_runtime.h>
#include <cstdint>

constexpr int B_   = 16;
constexpr int CIN  = 128;
constexpr int H_   = 224;
constexpr int W_   = 224;
constexpr int COUT = 256;
constexpr int HOUT = 112;
constexpr int WOUT = 75;

constexpr int OWP   = 80;     // padded ow per output row
constexpr int BM    = 160;    // 2 output rows
constexpr int CI_SC = 16;     // input channels per super-chunk
constexpr int KSC_R = 144;    // real k per super-chunk
constexpr int KP    = 160;    // padded k per super-chunk (5 x K=32)
constexpr int NSC   = 8;
constexpr int THREADS = 512;  // 8 waves: 2 m-halves x 4 co-groups (N=64 each)

constexpr int WS_ELEMS = COUT * KP * NSC;          // 327680 bf16
constexpr size_t WS_NEED = (size_t)WS_ELEMS * 2;   // 655360 B

typedef float  f32x4  __attribute__((ext_vector_type(4)));
typedef short  short8 __attribute__((ext_vector_type(8)));

struct U64x2 { unsigned long long lo, hi; };
__device__ inline short8 bc8(unsigned long long a, unsigned long long b) {
  U64x2 u{a, b};
  return __builtin_bit_cast(short8, u);
}

__device__ inline unsigned cvtpk(float a, float b) {
  unsigned r;
  asm("v_cvt_pk_bf16_f32 %0, %1, %2" : "=v"(r) : "v"(a), "v"(b));
  return r;  // lo16 = bf16(a), hi16 = bf16(b)
}

// ---- prepass: fp32 weights -> bf16 in ws, layout [co][sc][160], k>=144 zeroed ----
__global__ __launch_bounds__(256) void wprep(const float* __restrict__ wgt,
                                             uint2* __restrict__ ws) {
  int id = blockIdx.x * 256 + threadIdx.x;   // 81920 threads, 4 bf16 each
  int k4 = id % 40;
  int cs = id / 40;
  int sc = cs & 7;
  int co = cs >> 3;
  float f[4];
#pragma unroll
  for (int e = 0; e < 4; ++e) {
    int k = k4 * 4 + e;
    float v = 0.f;
    if (k < KSC_R) {
      int ci = k / 9, r = k - ci * 9;
      v = wgt[((size_t)co * CIN + sc * CI_SC + ci) * 9 + r];
    }
    f[e] = v;
  }
  ws[id] = make_uint2(cvtpk(f[0], f[1]), cvtpk(f[2], f[3]));
}

template <int WS>
__device__ __forceinline__ short8 load_b(const short8* p, const float* q, int kc, int g) {
  if (WS) {
    return p[kc * 4];
  } else {
    if (kc == 4 && g >= 2) return short8{};
    const float* s = q + kc * 32;
    float4 x0 = *(const float4*)s, x1 = *(const float4*)(s + 4);
    uint4 u{cvtpk(x0.x, x0.y), cvtpk(x0.z, x0.w), cvtpk(x1.x, x1.y), cvtpk(x1.z, x1.w)};
    return __builtin_bit_cast(short8, u);
  }
}

// issue the 10 tr reads for one K=32 chunk (5 m-frags x 2 k-halves)
#define TR_ISSUE(S, KC)                                                                   \
  {                                                                                       \
    unsigned a_ = abase + (unsigned)((KC) * 10240);                                       \
    asm volatile("ds_read_b64_tr_b16 %0, %1"             : "=v"(S##0) : "v"(a_));         \
    asm volatile("ds_read_b64_tr_b16 %0, %1 offset:1280" : "=v"(S##1) : "v"(a_));         \
    asm volatile("ds_read_b64_tr_b16 %0, %1 offset:128"  : "=v"(S##2) : "v"(a_));         \
    asm volatile("ds_read_b64_tr_b16 %0, %1 offset:1408" : "=v"(S##3) : "v"(a_));         \
    asm volatile("ds_read_b64_tr_b16 %0, %1 offset:256"  : "=v"(S##4) : "v"(a_));         \
    asm volatile("ds_read_b64_tr_b16 %0, %1 offset:1536" : "=v"(S##5) : "v"(a_));         \
    asm volatile("ds_read_b64_tr_b16 %0, %1 offset:384"  : "=v"(S##6) : "v"(a_));         \
    asm volatile("ds_read_b64_tr_b16 %0, %1 offset:1664" : "=v"(S##7) : "v"(a_));         \
    asm volatile("ds_read_b64_tr_b16 %0, %1 offset:512"  : "=v"(S##8) : "v"(a_));         \
    asm volatile("ds_read_b64_tr_b16 %0, %1 offset:1792" : "=v"(S##9) : "v"(a_));         \
  }

#define BLOAD(X, KC)                                                                      \
  X##0 = load_b<WS>(p0, q0, (KC), g);                                                     \
  X##1 = load_b<WS>(p1, q1, (KC), g);                                                     \
  X##2 = load_b<WS>(p2, q2, (KC), g);                                                     \
  X##3 = load_b<WS>(p3, q3, (KC), g);

#define WAITLG(N)                                                                         \
  asm volatile("s_waitcnt lgkmcnt(" #N ")" ::: "memory");                                 \
  __builtin_amdgcn_sched_barrier(0);

// 5 A-frags x 4 B-frags = 20 MFMAs
#define MFMA_SET(S, X)                                                                    \
  {                                                                                       \
    short8 a0_ = bc8(S##0, S##1);                                                         \
    short8 a1_ = bc8(S##2, S##3);                                                         \
    short8 a2_ = bc8(S##4, S##5);                                                         \
    short8 a3_ = bc8(S##6, S##7);                                                         \
    short8 a4_ = bc8(S##8, S##9);                                                         \
    __builtin_amdgcn_s_setprio(1);                                                        \
    acc[0][0] = __builtin_amdgcn_mfma_f32_16x16x32_bf16(a0_, X##0, acc[0][0], 0, 0, 0);   \
    acc[0][1] = __builtin_amdgcn_mfma_f32_16x16x32_bf16(a0_, X##1, acc[0][1], 0, 0, 0);   \
    acc[0][2] = __builtin_amdgcn_mfma_f32_16x16x32_bf16(a0_, X##2, acc[0][2], 0, 0, 0);   \
    acc[0][3] = __builtin_amdgcn_mfma_f32_16x16x32_bf16(a0_, X##3, acc[0][3], 0, 0, 0);   \
    acc[1][0] = __builtin_amdgcn_mfma_f32_16x16x32_bf16(a1_, X##0, acc[1][0], 0, 0, 0);   \
    acc[1][1] = __builtin_amdgcn_mfma_f32_16x16x32_bf16(a1_, X##1, acc[1][1], 0, 0, 0);   \
    acc[1][2] = __builtin_amdgcn_mfma_f32_16x16x32_bf16(a1_, X##2, acc[1][2], 0, 0, 0);   \
    acc[1][3] = __builtin_amdgcn_mfma_f32_16x16x32_bf16(a1_, X##3, acc[1][3], 0, 0, 0);   \
    acc[2][0] = __builtin_amdgcn_mfma_f32_16x16x32_bf16(a2_, X##0, acc[2][0], 0, 0, 0);   \
    acc[2][1] = __builtin_amdgcn_mfma_f32_16x16x32_bf16(a2_, X##1, acc[2][1], 0, 0, 0);   \
    acc[2][2] = __builtin_amdgcn_mfma_f32_16x16x32_bf16(a2_, X##2, acc[2][2], 0, 0, 0);   \
    acc[2][3] = __builtin_amdgcn_mfma_f32_16x16x32_bf16(a2_, X##3, acc[2][3], 0, 0, 0);   \
    acc[3][0] = __builtin_amdgcn_mfma_f32_16x16x32_bf16(a3_, X##0, acc[3][0], 0, 0, 0);   \
    acc[3][1] = __builtin_amdgcn_mfma_f32_16x16x32_bf16(a3_, X##1, acc[3][1], 0, 0, 0);   \
    acc[3][2] = __builtin_amdgcn_mfma_f32_16x16x32_bf16(a3_, X##2, acc[3][2], 0, 0, 0);   \
    acc[3][3] = __builtin_amdgcn_mfma_f32_16x16x32_bf16(a3_, X##3, acc[3][3], 0, 0, 0);   \
    acc[4][0] = __builtin_amdgcn_mfma_f32_16x16x32_bf16(a4_, X##0, acc[4][0], 0, 0, 0);   \
    acc[4][1] = __builtin_amdgcn_mfma_f32_16x16x32_bf16(a4_, X##1, acc[4][1], 0, 0, 0);   \
    acc[4][2] = __builtin_amdgcn_mfma_f32_16x16x32_bf16(a4_, X##2, acc[4][2], 0, 0, 0);   \
    acc[4][3] = __builtin_amdgcn_mfma_f32_16x16x32_bf16(a4_, X##3, acc[4][3], 0, 0, 0);   \
    __builtin_amdgcn_s_setprio(0);                                                        \
  }

template <int WS>
__global__ __launch_bounds__(THREADS, 2) void conv_mfma(
    const float* __restrict__ x, const float* __restrict__ wgt,
    const short8* __restrict__ wbf, const float* __restrict__ bias,
    float* __restrict__ out) {

  // LDS A-tile: [KP=160 k][BM=160 m] bf16, [4k x 16m] subtiles:
  // byte(k,m) = ((k>>2)*10 + (m>>4))*128 + (k&3)*32 + (m&15)*2   (51200 B)
  __shared__ __align__(16) unsigned char smem[KP * BM * 2];

  // XCD-chunked bijective swizzle: 896 blocks = 8 XCDs * 112
  int Lid   = (blockIdx.x & 7) * 112 + (blockIdx.x >> 3);
  int ohp   = Lid % 56;
  int b     = Lid / 56;
  int oh_base = ohp * 2;

  const int tid   = threadIdx.x;
  const int lane  = tid & 63;
  const int wv    = tid >> 6;
  const int mhalf = wv >> 2;          // 0,1 -> output row
  const int cogrp = wv & 3;           // 4 co-groups of 64
  const int g     = lane >> 4;        // k-lane-group
  const int l15   = lane & 15;

  const float* xb = x + (size_t)b * CIN * H_ * W_;
  const int coB_  = cogrp * 64 + l15;

  const unsigned sbase = (unsigned)(uintptr_t)&smem[0];
  const unsigned abase = sbase + (unsigned)(g * 2560 + mhalf * 640 + l15 * 8);

  // NaN fix: zero the never-staged k-rows 144..159 (contiguous 5120 B @46080).
  if (tid < 320) {
    *reinterpret_cast<uint4*>(&smem[46080 + tid * 16]) = uint4{0u, 0u, 0u, 0u};
  }

  // ---- sc-invariant staging precompute ----
  int      aoff[4], moff[4], coff[4];
  unsigned lb0[4], lb1[4], lb2[4], mA[4], mF[4];
#pragma unroll
  for (int j = 0; j < 4; ++j) {
    int it  = tid + THREADS * j;
    int ci  = it & 15;
    int r   = it >> 4;
    int gg  = r % 19;
    int t3  = r / 19;
    int kh  = t3 % 3;
    int ohl = t3 / 3;
    int ih  = 2 * (oh_base + ohl) - 1 + kh;
    bool rowok = (unsigned)ih < (unsigned)H_;
    int ro  = (ci * H_ + (rowok ? ih : 0)) * W_;
    int iwb = 12 * gg;
    aoff[j] = ro + iwb;
    moff[j] = ro + iwb - (gg ? 1 : 0);
    coff[j] = ro + (iwb + 8 > 220 ? 220 : iwb + 8);
    int k = ci * 9 + kh * 3;
    int m = ohl * OWP + 4 * gg;
    auto byteOf = [](int kk, int mm) -> unsigned {
      return (unsigned)(((kk >> 2) * 10 + (mm >> 4)) * 128 + (kk & 3) * 32 + (mm & 15) * 2);
    };
    lb0[j] = byteOf(k, m); lb1[j] = byteOf(k + 1, m); lb2[j] = byteOf(k + 2, m);
    mA[j] = rowok ? 0xFFFFFFFFu : 0u;
    mF[j] = mA[j] & (gg ? 0xFFFFFFFFu : 0xFFFF0000u);
  }

  f32x4 acc[5][4];
#pragma unroll
  for (int mf = 0; mf < 5; ++mf)
#pragma unroll
    for (int cf = 0; cf < 4; ++cf)
#pragma unroll
      for (int i = 0; i < 4; ++i) acc[mf][cf][i] = 0.f;

  unsigned long long tA0, tA1, tA2, tA3, tA4, tA5, tA6, tA7, tA8, tA9;
  unsigned long long tB0, tB1, tB2, tB3, tB4, tB5, tB6, tB7, tB8, tB9;
  short8 bA0, bA1, bA2, bA3, bB0, bB1, bB2, bB3;

  for (int sc = 0; sc < NSC; ++sc) {
    if (sc) __syncthreads();

    // ---- stage: vectorized fp32 loads -> cvtpk -> de-interleaved b64 LDS writes ----
    const float* xs = xb + (size_t)sc * (CI_SC * H_ * W_);
#pragma unroll
    for (int j = 0; j < 4; ++j) {
      if (j < 3 || tid < 288) {
        const float* ap = xs + aoff[j];
        float4 a4 = *(const float4*)ap;
        float4 b4 = *(const float4*)(ap + 4);
        float4 c4 = *(const float4*)(xs + coff[j]);
        float fm1 = xs[moff[j]];
        unsigned l0 = cvtpk(fm1,  a4.z) & mF[j];
        unsigned h0 = cvtpk(b4.y, c4.x) & mA[j];
        unsigned l1 = cvtpk(a4.x, a4.w) & mA[j];
        unsigned h1 = cvtpk(b4.z, c4.y) & mA[j];
        unsigned l2 = cvtpk(a4.y, b4.x) & mA[j];
        unsigned h2 = cvtpk(b4.w, c4.z) & mA[j];
        *(uint2*)&smem[lb0[j]] = make_uint2(l0, h0);
        *(uint2*)&smem[lb1[j]] = make_uint2(l1, h1);
        *(uint2*)&smem[lb2[j]] = make_uint2(l2, h2);
      }
    }
    __syncthreads();

    // ---- compute: 5 x K=32, tr-reads and B both double-buffered 1-deep ----
    const short8* p0 = wbf + (size_t)coB_ * 160 + sc * 20 + g;
    const short8* p1 = p0 + 16 * 160;
    const short8* p2 = p0 + 32 * 160;
    const short8* p3 = p0 + 48 * 160;
    const float*  q0 = wgt + (size_t)coB_ * 1152 + sc * 144 + g * 8;
    const float*  q1 = q0 + (size_t)16 * 1152;
    const float*  q2 = q0 + (size_t)32 * 1152;
    const float*  q3 = q0 + (size_t)48 * 1152;

    BLOAD(bA, 0)
    TR_ISSUE(tA, 0)
    BLOAD(bB, 1)
    TR_ISSUE(tB, 1)
    WAITLG(10)
    MFMA_SET(tA, bA)
    BLOAD(bA, 2)
    TR_ISSUE(tA, 2)
    WAITLG(10)
    MFMA_SET(tB, bB)
    BLOAD(bB, 3)
    TR_ISSUE(tB, 3)
    WAITLG(10)
    MFMA_SET(tA, bA)
    BLOAD(bA, 4)
    TR_ISSUE(tA, 4)
    WAITLG(10)
    MFMA_SET(tB, bB)
    WAITLG(0)
    MFMA_SET(tA, bA)
  }

  // ---- epilogue: C frag col(co)=l15, row(m)=g*4+r ----
  int oh = oh_base + mhalf;
  float bv0 = bias[coB_];
  float bv1 = bias[coB_ + 16];
  float bv2 = bias[coB_ + 32];
  float bv3 = bias[coB_ + 48];
  size_t ob0 = (((size_t)b * COUT + coB_) * HOUT + oh) * WOUT;
  size_t ob1 = ob0 + (size_t)16 * HOUT * WOUT;
  size_t ob2 = ob0 + (size_t)32 * HOUT * WOUT;
  size_t ob3 = ob0 + (size_t)48 * HOUT * WOUT;
#pragma unroll
  for (int mf = 0; mf < 5; ++mf) {
    int owb = mf * 16 + g * 4;
#pragma unroll
    for (int r = 0; r < 4; ++r) {
      int ow = owb + r;
      if (ow < WOUT) {
        out[ob0 + ow] = acc[mf][0][r] + bv0;
        out[ob1 + ow] = acc[mf][1][r] + bv1;
        out[ob2 + ow] = acc[mf][2][r] + bv2;
        out[ob3 + ow] = acc[mf][3][r] + bv3;
      }
    }
  }
}

extern "C" void kernel_launch(void* const* d_in, const int* in_sizes, int n_in,
                              void* d_out, int out_size, void* d_ws, size_t ws_size,
                              hipStream_t stream) {
  const float* x    = (const float*)d_in[0];
  const float* wgt  = (const float*)d_in[1];
  const float* bias = (const float*)d_in[2];
  float* out        = (float*)d_out;

  dim3 grid(16 * 56);
  dim3 block(THREADS);

  if (ws_size >= WS_NEED) {
    wprep<<<dim3(WS_ELEMS / 4 / 256), dim3(256), 0, stream>>>(wgt, (uint2*)d_ws);
    conv_mfma<1><<<grid, block, 0, stream>>>(x, wgt, (const short8*)d_ws, bias, out);
  } else {
    conv_mfma<0><<<grid, block, 0, stream>>>(x, wgt, (const short8*)d_ws, bias, out);
  }
}

// Round 7
// 206.323 us; speedup vs baseline: 2.2994x; 1.6710x over previous
//
#include <hip/hip_runtime.h>
#include <cstdint>

constexpr int B_   = 16;
constexpr int CIN  = 128;
constexpr int H_   = 224;
constexpr int W_   = 224;
constexpr int COUT = 256;
constexpr int HOUT = 112;
constexpr int WOUT = 75;

constexpr int OWP   = 80;     // padded ow per output row
constexpr int BM    = 160;    // 2 output rows
constexpr int CI_SC = 16;     // input channels per super-chunk
constexpr int KSC_R = 144;    // real k per super-chunk
constexpr int KP    = 160;    // padded k per super-chunk (5 x K=32)
constexpr int NSC   = 8;
constexpr int THREADS = 512;  // 8 waves: 2 m-halves x 4 co-groups (N=64 each)

constexpr int WS_SH8  = COUT * KP * NSC / 8;       // 40960 short8 slots
constexpr size_t WS_NEED = (size_t)WS_SH8 * 16;    // 655360 B

typedef float  f32x4  __attribute__((ext_vector_type(4)));
typedef short  short8 __attribute__((ext_vector_type(8)));

struct U64x2 { unsigned long long lo, hi; };
__device__ inline short8 bc8(unsigned long long a, unsigned long long b) {
  U64x2 u{a, b};
  return __builtin_bit_cast(short8, u);
}

__device__ inline unsigned cvtpk(float a, float b) {
  unsigned r;
  asm("v_cvt_pk_bf16_f32 %0, %1, %2" : "=v"(r) : "v"(a), "v"(b));
  return r;  // lo16 = bf16(a), hi16 = bf16(b)
}

// ---- prepass: fp32 weights -> bf16, layout [sc][kc][g][co][8k] (coalesced B frags) ----
__global__ __launch_bounds__(256) void wprep(const float* __restrict__ wgt,
                                             uint4* __restrict__ ws) {
  int o  = blockIdx.x * 256 + threadIdx.x;   // 40960 short8 outputs
  int co = o & 255;
  int t  = o >> 8;          // 0..159
  int g  = t & 3;
  int u  = t >> 2;          // 0..39
  int kc = u % 5;
  int sc = u / 5;
  int kloc = kc * 32 + g * 8;                // k within super-chunk
  float f[8];
  if (kloc < KSC_R) {
    const float* p = wgt + (size_t)co * 1152 + sc * KSC_R + kloc;  // 8-aligned
    float4 a = *(const float4*)p;
    float4 b = *(const float4*)(p + 4);
    f[0] = a.x; f[1] = a.y; f[2] = a.z; f[3] = a.w;
    f[4] = b.x; f[5] = b.y; f[6] = b.z; f[7] = b.w;
  } else {
#pragma unroll
    for (int e = 0; e < 8; ++e) f[e] = 0.f;
  }
  ws[o] = uint4{cvtpk(f[0], f[1]), cvtpk(f[2], f[3]), cvtpk(f[4], f[5]), cvtpk(f[6], f[7])};
}

// fallback (no ws): convert from fp32 weights in-flight (uncoalesced, slow but correct)
__device__ __forceinline__ short8 load_bq(const float* q, int kc, int g) {
  if (kc == 4 && g >= 2) return short8{};
  const float* s = q + kc * 32;
  float4 x0 = *(const float4*)s, x1 = *(const float4*)(s + 4);
  uint4 u{cvtpk(x0.x, x0.y), cvtpk(x0.z, x0.w), cvtpk(x1.x, x1.y), cvtpk(x1.z, x1.w)};
  return __builtin_bit_cast(short8, u);
}

// issue the 10 tr reads for one K=32 chunk (5 m-frags x 2 k-halves)
#define TR_ISSUE(S, KC)                                                                   \
  {                                                                                       \
    unsigned a_ = abase + (unsigned)((KC) * 10240);                                       \
    asm volatile("ds_read_b64_tr_b16 %0, %1"             : "=v"(S##0) : "v"(a_));         \
    asm volatile("ds_read_b64_tr_b16 %0, %1 offset:1280" : "=v"(S##1) : "v"(a_));         \
    asm volatile("ds_read_b64_tr_b16 %0, %1 offset:128"  : "=v"(S##2) : "v"(a_));         \
    asm volatile("ds_read_b64_tr_b16 %0, %1 offset:1408" : "=v"(S##3) : "v"(a_));         \
    asm volatile("ds_read_b64_tr_b16 %0, %1 offset:256"  : "=v"(S##4) : "v"(a_));         \
    asm volatile("ds_read_b64_tr_b16 %0, %1 offset:1536" : "=v"(S##5) : "v"(a_));         \
    asm volatile("ds_read_b64_tr_b16 %0, %1 offset:384"  : "=v"(S##6) : "v"(a_));         \
    asm volatile("ds_read_b64_tr_b16 %0, %1 offset:1664" : "=v"(S##7) : "v"(a_));         \
    asm volatile("ds_read_b64_tr_b16 %0, %1 offset:512"  : "=v"(S##8) : "v"(a_));         \
    asm volatile("ds_read_b64_tr_b16 %0, %1 offset:1792" : "=v"(S##9) : "v"(a_));         \
  }

// B frags: ws layout gives lane-contiguous 16B x 16-lane segments per frag
#define BLOAD(X, KC)                                                                      \
  if (WS) {                                                                               \
    X##0 = wsb[(KC) * 1024];                                                              \
    X##1 = wsb[(KC) * 1024 + 16];                                                         \
    X##2 = wsb[(KC) * 1024 + 32];                                                         \
    X##3 = wsb[(KC) * 1024 + 48];                                                         \
  } else {                                                                                \
    X##0 = load_bq(q0, (KC), g);                                                          \
    X##1 = load_bq(q1, (KC), g);                                                          \
    X##2 = load_bq(q2, (KC), g);                                                          \
    X##3 = load_bq(q3, (KC), g);                                                          \
  }

#define WAITLG(N)                                                                         \
  asm volatile("s_waitcnt lgkmcnt(" #N ")" ::: "memory");                                 \
  __builtin_amdgcn_sched_barrier(0);

// 5 A-frags x 4 B-frags = 20 MFMAs
#define MFMA_SET(S, X)                                                                    \
  {                                                                                       \
    short8 a0_ = bc8(S##0, S##1);                                                         \
    short8 a1_ = bc8(S##2, S##3);                                                         \
    short8 a2_ = bc8(S##4, S##5);                                                         \
    short8 a3_ = bc8(S##6, S##7);                                                         \
    short8 a4_ = bc8(S##8, S##9);                                                         \
    __builtin_amdgcn_s_setprio(1);                                                        \
    acc[0][0] = __builtin_amdgcn_mfma_f32_16x16x32_bf16(a0_, X##0, acc[0][0], 0, 0, 0);   \
    acc[0][1] = __builtin_amdgcn_mfma_f32_16x16x32_bf16(a0_, X##1, acc[0][1], 0, 0, 0);   \
    acc[0][2] = __builtin_amdgcn_mfma_f32_16x16x32_bf16(a0_, X##2, acc[0][2], 0, 0, 0);   \
    acc[0][3] = __builtin_amdgcn_mfma_f32_16x16x32_bf16(a0_, X##3, acc[0][3], 0, 0, 0);   \
    acc[1][0] = __builtin_amdgcn_mfma_f32_16x16x32_bf16(a1_, X##0, acc[1][0], 0, 0, 0);   \
    acc[1][1] = __builtin_amdgcn_mfma_f32_16x16x32_bf16(a1_, X##1, acc[1][1], 0, 0, 0);   \
    acc[1][2] = __builtin_amdgcn_mfma_f32_16x16x32_bf16(a1_, X##2, acc[1][2], 0, 0, 0);   \
    acc[1][3] = __builtin_amdgcn_mfma_f32_16x16x32_bf16(a1_, X##3, acc[1][3], 0, 0, 0);   \
    acc[2][0] = __builtin_amdgcn_mfma_f32_16x16x32_bf16(a2_, X##0, acc[2][0], 0, 0, 0);   \
    acc[2][1] = __builtin_amdgcn_mfma_f32_16x16x32_bf16(a2_, X##1, acc[2][1], 0, 0, 0);   \
    acc[2][2] = __builtin_amdgcn_mfma_f32_16x16x32_bf16(a2_, X##2, acc[2][2], 0, 0, 0);   \
    acc[2][3] = __builtin_amdgcn_mfma_f32_16x16x32_bf16(a2_, X##3, acc[2][3], 0, 0, 0);   \
    acc[3][0] = __builtin_amdgcn_mfma_f32_16x16x32_bf16(a3_, X##0, acc[3][0], 0, 0, 0);   \
    acc[3][1] = __builtin_amdgcn_mfma_f32_16x16x32_bf16(a3_, X##1, acc[3][1], 0, 0, 0);   \
    acc[3][2] = __builtin_amdgcn_mfma_f32_16x16x32_bf16(a3_, X##2, acc[3][2], 0, 0, 0);   \
    acc[3][3] = __builtin_amdgcn_mfma_f32_16x16x32_bf16(a3_, X##3, acc[3][3], 0, 0, 0);   \
    acc[4][0] = __builtin_amdgcn_mfma_f32_16x16x32_bf16(a4_, X##0, acc[4][0], 0, 0, 0);   \
    acc[4][1] = __builtin_amdgcn_mfma_f32_16x16x32_bf16(a4_, X##1, acc[4][1], 0, 0, 0);   \
    acc[4][2] = __builtin_amdgcn_mfma_f32_16x16x32_bf16(a4_, X##2, acc[4][2], 0, 0, 0);   \
    acc[4][3] = __builtin_amdgcn_mfma_f32_16x16x32_bf16(a4_, X##3, acc[4][3], 0, 0, 0);   \
    __builtin_amdgcn_s_setprio(0);                                                        \
  }

template <int WS>
__global__ __launch_bounds__(THREADS, 2) void conv_mfma(
    const float* __restrict__ x, const float* __restrict__ wgt,
    const short8* __restrict__ wbf, const float* __restrict__ bias,
    float* __restrict__ out) {

  // LDS A-tile: [KP=160 k][BM=160 m] bf16, [4k x 16m] subtiles:
  // byte(k,m) = ((k>>2)*10 + (m>>4))*128 + (k&3)*32 + (m&15)*2   (51200 B)
  __shared__ __align__(16) unsigned char smem[KP * BM * 2];

  // XCD-chunked bijective swizzle: 896 blocks = 8 XCDs * 112
  int Lid   = (blockIdx.x & 7) * 112 + (blockIdx.x >> 3);
  int ohp   = Lid % 56;
  int b     = Lid / 56;
  int oh_base = ohp * 2;

  const int tid   = threadIdx.x;
  const int lane  = tid & 63;
  const int wv    = tid >> 6;
  const int mhalf = wv >> 2;          // 0,1 -> output row
  const int cogrp = wv & 3;           // 4 co-groups of 64
  const int g     = lane >> 4;        // k-lane-group
  const int l15   = lane & 15;

  const float* xb = x + (size_t)b * CIN * H_ * W_;
  const int coB_  = cogrp * 64 + l15;

  const unsigned sbase = (unsigned)(uintptr_t)&smem[0];
  const unsigned abase = sbase + (unsigned)(g * 2560 + mhalf * 640 + l15 * 8);

  // NaN fix: zero the never-staged k-rows 144..159 (contiguous 5120 B @46080).
  if (tid < 320) {
    *reinterpret_cast<uint4*>(&smem[46080 + tid * 16]) = uint4{0u, 0u, 0u, 0u};
  }

  // ---- sc-invariant staging precompute; gg fastest over lanes => coalesced rows ----
  int      aoff[4], moff[4], coff[4];
  unsigned lb0[4], lb1[4], lb2[4], mA[4], mF[4];
#pragma unroll
  for (int j = 0; j < 4; ++j) {
    int it  = tid + THREADS * j;
    int gg  = it % 19;                 // lane-fastest: consecutive lanes, same row
    int rid = it / 19;                 // 0..95
    int ci  = rid & 15;
    int t3  = rid >> 4;
    int kh  = t3 % 3;
    int ohl = t3 / 3;
    int ih  = 2 * (oh_base + ohl) - 1 + kh;
    bool rowok = (unsigned)ih < (unsigned)H_;
    int ro  = (ci * H_ + (rowok ? ih : 0)) * W_;
    int iwb = 12 * gg;
    aoff[j] = ro + iwb;
    moff[j] = ro + iwb - (gg ? 1 : 0);
    coff[j] = ro + (iwb + 8 > 220 ? 220 : iwb + 8);
    int k = ci * 9 + kh * 3;
    int m = ohl * OWP + 4 * gg;
    auto byteOf = [](int kk, int mm) -> unsigned {
      return (unsigned)(((kk >> 2) * 10 + (mm >> 4)) * 128 + (kk & 3) * 32 + (mm & 15) * 2);
    };
    lb0[j] = byteOf(k, m); lb1[j] = byteOf(k + 1, m); lb2[j] = byteOf(k + 2, m);
    mA[j] = rowok ? 0xFFFFFFFFu : 0u;
    mF[j] = mA[j] & (gg ? 0xFFFFFFFFu : 0xFFFF0000u);
  }

  f32x4 acc[5][4];
#pragma unroll
  for (int mf = 0; mf < 5; ++mf)
#pragma unroll
    for (int cf = 0; cf < 4; ++cf)
#pragma unroll
      for (int i = 0; i < 4; ++i) acc[mf][cf][i] = 0.f;

  unsigned long long tA0, tA1, tA2, tA3, tA4, tA5, tA6, tA7, tA8, tA9;
  unsigned long long tB0, tB1, tB2, tB3, tB4, tB5, tB6, tB7, tB8, tB9;
  short8 bA0, bA1, bA2, bA3, bB0, bB1, bB2, bB3;

  for (int sc = 0; sc < NSC; ++sc) {
    if (sc) __syncthreads();

    // ---- stage: coalesced fp32 loads -> cvtpk -> de-interleaved b64 LDS writes ----
    const float* xs = xb + (size_t)sc * (CI_SC * H_ * W_);
#pragma unroll
    for (int j = 0; j < 4; ++j) {
      if (j < 3 || tid < 288) {
        const float* ap = xs + aoff[j];
        float4 a4 = *(const float4*)ap;
        float4 b4 = *(const float4*)(ap + 4);
        float4 c4 = *(const float4*)(xs + coff[j]);
        float fm1 = xs[moff[j]];
        unsigned l0 = cvtpk(fm1,  a4.z) & mF[j];
        unsigned h0 = cvtpk(b4.y, c4.x) & mA[j];
        unsigned l1 = cvtpk(a4.x, a4.w) & mA[j];
        unsigned h1 = cvtpk(b4.z, c4.y) & mA[j];
        unsigned l2 = cvtpk(a4.y, b4.x) & mA[j];
        unsigned h2 = cvtpk(b4.w, c4.z) & mA[j];
        *(uint2*)&smem[lb0[j]] = make_uint2(l0, h0);
        *(uint2*)&smem[lb1[j]] = make_uint2(l1, h1);
        *(uint2*)&smem[lb2[j]] = make_uint2(l2, h2);
      }
    }
    __syncthreads();

    // ---- compute: 5 x K=32, tr-reads and B both double-buffered 1-deep ----
    const short8* wsb = wbf + (size_t)sc * 5120 + g * 256 + cogrp * 64 + l15;
    const float*  q0 = wgt + (size_t)coB_ * 1152 + sc * 144 + g * 8;
    const float*  q1 = q0 + (size_t)16 * 1152;
    const float*  q2 = q0 + (size_t)32 * 1152;
    const float*  q3 = q0 + (size_t)48 * 1152;

    BLOAD(bA, 0)
    TR_ISSUE(tA, 0)
    BLOAD(bB, 1)
    TR_ISSUE(tB, 1)
    WAITLG(10)
    MFMA_SET(tA, bA)
    BLOAD(bA, 2)
    TR_ISSUE(tA, 2)
    WAITLG(10)
    MFMA_SET(tB, bB)
    BLOAD(bB, 3)
    TR_ISSUE(tB, 3)
    WAITLG(10)
    MFMA_SET(tA, bA)
    BLOAD(bA, 4)
    TR_ISSUE(tA, 4)
    WAITLG(10)
    MFMA_SET(tB, bB)
    WAITLG(0)
    MFMA_SET(tA, bA)
  }

  // ---- epilogue: C frag col(co)=l15, row(m)=g*4+r ----
  int oh = oh_base + mhalf;
  float bv0 = bias[coB_];
  float bv1 = bias[coB_ + 16];
  float bv2 = bias[coB_ + 32];
  float bv3 = bias[coB_ + 48];
  size_t ob0 = (((size_t)b * COUT + coB_) * HOUT + oh) * WOUT;
  size_t ob1 = ob0 + (size_t)16 * HOUT * WOUT;
  size_t ob2 = ob0 + (size_t)32 * HOUT * WOUT;
  size_t ob3 = ob0 + (size_t)48 * HOUT * WOUT;
#pragma unroll
  for (int mf = 0; mf < 5; ++mf) {
    int owb = mf * 16 + g * 4;
#pragma unroll
    for (int r = 0; r < 4; ++r) {
      int ow = owb + r;
      if (ow < WOUT) {
        out[ob0 + ow] = acc[mf][0][r] + bv0;
        out[ob1 + ow] = acc[mf][1][r] + bv1;
        out[ob2 + ow] = acc[mf][2][r] + bv2;
        out[ob3 + ow] = acc[mf][3][r] + bv3;
      }
    }
  }
}

extern "C" void kernel_launch(void* const* d_in, const int* in_sizes, int n_in,
                              void* d_out, int out_size, void* d_ws, size_t ws_size,
                              hipStream_t stream) {
  const float* x    = (const float*)d_in[0];
  const float* wgt  = (const float*)d_in[1];
  const float* bias = (const float*)d_in[2];
  float* out        = (float*)d_out;

  dim3 grid(16 * 56);
  dim3 block(THREADS);

  if (ws_size >= WS_NEED) {
    wprep<<<dim3(WS_SH8 / 256), dim3(256), 0, stream>>>(wgt, (uint4*)d_ws);
    conv_mfma<1><<<grid, block, 0, stream>>>(x, wgt, (const short8*)d_ws, bias, out);
  } else {
    conv_mfma<0><<<grid, block, 0, stream>>>(x, wgt, (const short8*)d_ws, bias, out);
  }
}